// Round 18
// baseline (329.129 us; speedup 1.0000x reference)
//
#include <hip/hip_runtime.h>

typedef _Float16 f16;
typedef _Float16 f16x2 __attribute__((ext_vector_type(2)));
typedef _Float16 f16x4 __attribute__((ext_vector_type(4)));
typedef _Float16 f16x8 __attribute__((ext_vector_type(8)));
typedef float f32x4 __attribute__((ext_vector_type(4)));

#define NLOG2E -1.4426950408889634f
#define NC2LE  -2.8853900817779268f

__device__ __forceinline__ float fastrcp(float x) { return __builtin_amdgcn_rcpf(x); }
__device__ __forceinline__ float fexp2(float x) { return __builtin_amdgcn_exp2f(x); }

#define TT 512
#define NB 8
/* xpack: f16 [NB][TT][8] = [x0..x5,0,0] per t; per-batch stride 4104 f16 = 2052 dw (==4 mod 32) */
#define XPS (TT * 8 + 8)
#define XP_ELE (NB * XPS)            /* 32832 */
/* aug: [h2(64)|h1(64)|slack] stride 184 f16 = 368B */
#define AUGS 184
#define A0OFF XP_ELE
#define A1OFF (A0OFF + NB * AUGS)
#define LDS_F16 (A1OFF + NB * AUGS)  /* 35776 */
#define LDS_BYTES (LDS_F16 * 2)      /* 71552 B */

__device__ __forceinline__ f16x8 cvt8s(const float* p, float s) {
  f32x4 a = *(const f32x4*)p;
  f32x4 b = *(const f32x4*)(p + 4);
  f16x8 r;
  #pragma unroll
  for (int i = 0; i < 4; ++i) { r[i] = (f16)(a[i] * s); r[4 + i] = (f16)(b[i] * s); }
  return r;
}

__global__ __launch_bounds__(512, 2)
void lstm2_kernel(const float* __restrict__ x,
                  const float* __restrict__ Wih0, const float* __restrict__ Whh0,
                  const float* __restrict__ bih0, const float* __restrict__ bhh0,
                  const float* __restrict__ Wih1, const float* __restrict__ Whh1,
                  const float* __restrict__ bih1, const float* __restrict__ bhh1,
                  const float* __restrict__ Wlin, const float* __restrict__ blin,
                  float* __restrict__ out)
{
  extern __shared__ f16 lds[];
  f16* xpack = lds;
  f16* aug0 = lds + A0OFF;
  f16* aug1 = lds + A1OFF;

  const int tid = threadIdx.x;
  const int wv = tid >> 6;
  const int team = wv >> 2;        // 0: layer-0 stage, 1: layer-1 stage
  const int uw = wv & 3;           // unit group [16*uw, 16*uw+16)
  const int lane = tid & 63;
  const int m = lane & 15;         // B col; batches = cols 0..7, cols 8..15 mirror
  const int q = lane >> 4;         // k-quarter / C row group
  const bool lohalf = (m < 8);
  const int bcol = m & 7;          // this lane's batch

  // ---- stationary NEGATED-prescaled weights (A fragments) + biases ----
  f16x8 af[4][4];
  f32x4 bv[4];
  #pragma unroll
  for (int g = 0; g < 4; ++g) {
    const float sg = (g == 2) ? NC2LE : NLOG2E;
    const int R = g * 64 + 16 * uw + m;
    if (team == 1) {
      af[g][0] = cvt8s(&Whh1[R * 64 + 8 * q], sg);
      af[g][1] = cvt8s(&Whh1[R * 64 + 32 + 8 * q], sg);
      af[g][2] = cvt8s(&Wih1[R * 64 + 8 * q], sg);
      af[g][3] = cvt8s(&Wih1[R * 64 + 32 + 8 * q], sg);
    } else {
      af[g][0] = cvt8s(&Whh0[R * 64 + 8 * q], sg);
      af[g][1] = cvt8s(&Whh0[R * 64 + 32 + 8 * q], sg);
      f16x8 t;
      #pragma unroll
      for (int i = 0; i < 8; ++i) t[i] = (f16)0.0f;
      if (q == 0) {
        #pragma unroll
        for (int i = 0; i < 6; ++i) t[i] = (f16)(Wih0[R * 6 + i] * sg);
      }
      af[g][2] = t;
      af[g][3] = t;  // unused by team 0
    }
    const float* bi = (team == 1) ? bih1 : bih0;
    const float* bh = (team == 1) ? bhh1 : bhh0;
    const int U = g * 64 + 16 * uw + 4 * q;
    #pragma unroll
    for (int r = 0; r < 4; ++r) bv[g][r] = (bi[U + r] + bh[U + r]) * sg;
  }

  // ---- stage x -> LDS pre-packed [x0..x5,0,0] per timestep ----
  {
    const float* xblk = x + (size_t)blockIdx.x * (NB * TT * 6);
    #pragma unroll 1
    for (int idx = tid; idx < NB * TT; idx += 512) {
      const int n = idx >> 9;        // batch
      const int t = idx & (TT - 1);
      const float* src = xblk + n * (TT * 6) + t * 6;
      f16* dst = xpack + n * XPS + t * 8;
      f16x4 h0, h1;
      h0[0] = (f16)src[0]; h0[1] = (f16)src[1]; h0[2] = (f16)src[2]; h0[3] = (f16)src[3];
      h1[0] = (f16)src[4]; h1[1] = (f16)src[5]; h1[2] = (f16)0.0f; h1[3] = (f16)0.0f;
      *(f16x4*)&dst[0] = h0;
      *(f16x4*)&dst[4] = h1;
    }
  }
  for (int idx = tid; idx < NB * AUGS; idx += 512) aug0[idx] = (f16)0.0f;
  __syncthreads();

  float cs0 = 0.0f, cs1 = 0.0f;

  const int colb = bcol * AUGS;
  const int xofs = bcol * XPS;
  const int rowofs = 16 * uw + 4 * q + (lohalf ? 0 : 2);

  f32x4 z4;
  #pragma unroll
  for (int r = 0; r < 4; ++r) z4[r] = 0.0f;

  auto finish1 = [&](float ai, float afv, float ag, float ao, float& cs) -> f16 {
    float A = 1.0f + fexp2(ai);       // e^{-i}+1 (acc pre-negated)
    float B = 1.0f + fexp2(afv);
    float G = 1.0f + fexp2(ag);       // e^{-2g}+1
    float O = 1.0f + fexp2(ao);
    float d1 = fastrcp(A * B);
    float d2 = fastrcp(G * O);
    float si = d1 * B;
    float sf = d1 * A;
    float tg = __builtin_fmaf(2.0f, d2 * O, -1.0f);
    float so = d2 * G;
    float cn = __builtin_fmaf(sf, cs, si * tg);
    cs = cn;
    float T = 1.0f + fexp2(cn * NC2LE);
    float rT = fastrcp(T);
    return (f16)(__builtin_fmaf(2.0f * so, rT, -so));
  };

  auto compact_finish = [&](const f32x4* acc) -> f16x2 {
    float u0[4], u1[4];
    #pragma unroll
    for (int g = 0; g < 4; ++g) {
      u0[g] = lohalf ? acc[g][0] : acc[g][2];
      u1[g] = lohalf ? acc[g][1] : acc[g][3];
    }
    f16x2 ho;
    ho[0] = finish1(u0[0], u0[1], u0[2], u0[3], cs0);
    ho[1] = finish1(u1[0], u1[1], u1[2], u1[3], cs1);
    return ho;
  };

  // one pipeline step; all ds_reads issued before the MFMA cluster
  auto STEP = [&](f16* cur, f16* nxt, int t) {
    f16x8 Bh1a = *(const f16x8*)&cur[colb + 64 + 8 * q];
    f16x8 Bh1b = *(const f16x8*)&cur[colb + 96 + 8 * q];
    if (team == 1) {
      f16x8 Bh2a = *(const f16x8*)&cur[colb + 0 + 8 * q];
      f16x8 Bh2b = *(const f16x8*)&cur[colb + 32 + 8 * q];
      f32x4 acc[4];
      __builtin_amdgcn_s_setprio(1);
      #pragma unroll
      for (int g = 0; g < 4; ++g) {
        f32x4 p = __builtin_amdgcn_mfma_f32_16x16x32_f16(af[g][0], Bh2a, bv[g], 0, 0, 0);
        f32x4 s = __builtin_amdgcn_mfma_f32_16x16x32_f16(af[g][1], Bh2b, z4, 0, 0, 0);
        p = __builtin_amdgcn_mfma_f32_16x16x32_f16(af[g][2], Bh1a, p, 0, 0, 0);
        s = __builtin_amdgcn_mfma_f32_16x16x32_f16(af[g][3], Bh1b, s, 0, 0, 0);
        acc[g] = p + s;
      }
      __builtin_amdgcn_s_setprio(0);
      f16x2 h2o = compact_finish(acc);
      *(f16x2*)&nxt[colb + rowofs] = h2o;                // h2(t)
    } else {
      f16x8 bx = *(const f16x8*)&xpack[xofs + (t + 1) * 8];
      f32x4 acc[4];
      __builtin_amdgcn_s_setprio(1);
      #pragma unroll
      for (int g = 0; g < 4; ++g) {
        f32x4 p = __builtin_amdgcn_mfma_f32_16x16x32_f16(af[g][0], Bh1a, bv[g], 0, 0, 0);
        f32x4 s = __builtin_amdgcn_mfma_f32_16x16x32_f16(af[g][1], Bh1b, z4, 0, 0, 0);
        s = __builtin_amdgcn_mfma_f32_16x16x32_f16(af[g][2], bx, s, 0, 0, 0);
        acc[g] = p + s;
      }
      __builtin_amdgcn_s_setprio(0);
      f16x2 h1o = compact_finish(acc);
      *(f16x2*)&nxt[colb + 64 + rowofs] = h1o;           // h1(t+1)
    }
    __syncthreads();
  };

  // ---- prologue: team0 computes h1(0) = L0(x(0), 0) ----
  if (team == 0) {
    f16x8 bx = *(const f16x8*)&xpack[xofs + 0];
    f32x4 acc[4];
    #pragma unroll
    for (int g = 0; g < 4; ++g)
      acc[g] = __builtin_amdgcn_mfma_f32_16x16x32_f16(af[g][2], bx, bv[g], 0, 0, 0);
    f16x2 h1o = compact_finish(acc);
    *(f16x2*)&aug0[colb + 64 + rowofs] = h1o;
  }
  __syncthreads();

  // ---- main loop: 511 steps, unrolled x2, compile-time buffers ----
  #pragma unroll 1
  for (int t = 0; t < TT - 2; t += 2) {
    STEP(aug0, aug1, t);
    STEP(aug1, aug0, t + 1);
  }
  STEP(aug0, aug1, TT - 2);   // t = 510; aug1 = {h2(510), h1(511)}

  // ---- epilogue: team1 computes h2(511) from aug1 into aug0 ----
  if (team == 1) {
    f16x8 Bh2a = *(const f16x8*)&aug1[colb + 0 + 8 * q];
    f16x8 Bh2b = *(const f16x8*)&aug1[colb + 32 + 8 * q];
    f16x8 Bh1a = *(const f16x8*)&aug1[colb + 64 + 8 * q];
    f16x8 Bh1b = *(const f16x8*)&aug1[colb + 96 + 8 * q];
    f32x4 acc[4];
    #pragma unroll
    for (int g = 0; g < 4; ++g) {
      f32x4 p = __builtin_amdgcn_mfma_f32_16x16x32_f16(af[g][0], Bh2a, bv[g], 0, 0, 0);
      f32x4 s = __builtin_amdgcn_mfma_f32_16x16x32_f16(af[g][1], Bh2b, z4, 0, 0, 0);
      p = __builtin_amdgcn_mfma_f32_16x16x32_f16(af[g][2], Bh1a, p, 0, 0, 0);
      s = __builtin_amdgcn_mfma_f32_16x16x32_f16(af[g][3], Bh1b, s, 0, 0, 0);
      acc[g] = p + s;
    }
    f16x2 h2o = compact_finish(acc);
    *(f16x2*)&aug0[colb + rowofs] = h2o;
  }
  __syncthreads();

  // ---- final linear: out[b] = Wlin . h2(511) + blin ----
  if (tid < 48) {
    const int bl = tid / 6, o = tid - bl * 6;
    float s = blin[o];
    const float* wl = &Wlin[o * 64];
    #pragma unroll 8
    for (int u = 0; u < 64; ++u) s += wl[u] * (float)aug0[bl * AUGS + u];
    out[(blockIdx.x * NB + bl) * 6 + o] = s;
  }
}

extern "C" void kernel_launch(void* const* d_in, const int* in_sizes, int n_in,
                              void* d_out, int out_size, void* d_ws, size_t ws_size,
                              hipStream_t stream) {
  const float* xp    = (const float*)d_in[0];
  const float* Wih0  = (const float*)d_in[1];
  const float* Whh0  = (const float*)d_in[2];
  const float* bih0  = (const float*)d_in[3];
  const float* bhh0  = (const float*)d_in[4];
  const float* Wih1  = (const float*)d_in[5];
  const float* Whh1  = (const float*)d_in[6];
  const float* bih1  = (const float*)d_in[7];
  const float* bhh1  = (const float*)d_in[8];
  const float* Wlin  = (const float*)d_in[9];
  const float* blin  = (const float*)d_in[10];
  float* outp = (float*)d_out;

  hipFuncSetAttribute(reinterpret_cast<const void*>(lstm2_kernel),
                      hipFuncAttributeMaxDynamicSharedMemorySize, LDS_BYTES);
  lstm2_kernel<<<256, 512, LDS_BYTES, stream>>>(xp, Wih0, Whh0, bih0, bhh0,
                                                Wih1, Whh1, bih1, bhh1,
                                                Wlin, blin, outp);
}

// Round 19
// 277.384 us; speedup vs baseline: 1.1865x; 1.1865x over previous
//
#include <hip/hip_runtime.h>

typedef _Float16 f16;
typedef _Float16 f16x2 __attribute__((ext_vector_type(2)));
typedef _Float16 f16x4 __attribute__((ext_vector_type(4)));
typedef _Float16 f16x8 __attribute__((ext_vector_type(8)));
typedef float f32x4 __attribute__((ext_vector_type(4)));

#define NLOG2E -1.4426950408889634f
#define NC2LE  -2.8853900817779268f

__device__ __forceinline__ float fastrcp(float x) { return __builtin_amdgcn_rcpf(x); }
__device__ __forceinline__ float fexp2(float x) { return __builtin_amdgcn_exp2f(x); }

#define TT 512
#define NB 8
/* xstage: f16 [NB][3080] raw x; dw stride 1540 */
#define XBS 3080
#define XS_ELE (NB * XBS)            /* 24640 */
/* aug: [h2(64)|h1(64)|slack] stride 184 f16 = 368B */
#define AUGS 184
#define A0OFF XS_ELE
#define A1OFF (A0OFF + NB * AUGS)
#define LDS_F16 (A1OFF + NB * AUGS)  /* 27584 */
#define LDS_BYTES (LDS_F16 * 2)      /* 55168 B */

__device__ __forceinline__ f16x8 cvt8s(const float* p, float s) {
  f32x4 a = *(const f32x4*)p;
  f32x4 b = *(const f32x4*)(p + 4);
  f16x8 r;
  #pragma unroll
  for (int i = 0; i < 4; ++i) { r[i] = (f16)(a[i] * s); r[4 + i] = (f16)(b[i] * s); }
  return r;
}

__global__ __launch_bounds__(512, 2)
void lstm2_kernel(const float* __restrict__ x,
                  const float* __restrict__ Wih0, const float* __restrict__ Whh0,
                  const float* __restrict__ bih0, const float* __restrict__ bhh0,
                  const float* __restrict__ Wih1, const float* __restrict__ Whh1,
                  const float* __restrict__ bih1, const float* __restrict__ bhh1,
                  const float* __restrict__ Wlin, const float* __restrict__ blin,
                  float* __restrict__ out)
{
  extern __shared__ f16 lds[];
  f16* xstage = lds;
  f16* aug0 = lds + A0OFF;
  f16* aug1 = lds + A1OFF;
  const unsigned int* xw = (const unsigned int*)xstage;

  const int tid = threadIdx.x;
  const int wv = tid >> 6;
  const int team = wv >> 2;        // 0: layer-0 stage, 1: layer-1 stage
  const int uw = wv & 3;           // unit group [16*uw, 16*uw+16)
  const int lane = tid & 63;
  const int m = lane & 15;         // B col; batches = cols 0..7, cols 8..15 mirror
  const int q = lane >> 4;         // k-quarter / C row group
  const bool lohalf = (m < 8);
  const int bcol = m & 7;          // this lane's batch

  // ---- stationary NEGATED-prescaled weights (A fragments) + biases ----
  // gates scaled by -log2e (g by -2*log2e) so pointwise uses exp2(acc) directly
  f16x8 af[4][4];
  f32x4 bv[4];
  #pragma unroll
  for (int g = 0; g < 4; ++g) {
    const float sg = (g == 2) ? NC2LE : NLOG2E;
    const int R = g * 64 + 16 * uw + m;
    if (team == 1) {
      af[g][0] = cvt8s(&Whh1[R * 64 + 8 * q], sg);
      af[g][1] = cvt8s(&Whh1[R * 64 + 32 + 8 * q], sg);
      af[g][2] = cvt8s(&Wih1[R * 64 + 8 * q], sg);
      af[g][3] = cvt8s(&Wih1[R * 64 + 32 + 8 * q], sg);
    } else {
      af[g][0] = cvt8s(&Whh0[R * 64 + 8 * q], sg);
      af[g][1] = cvt8s(&Whh0[R * 64 + 32 + 8 * q], sg);
      f16x8 t;
      #pragma unroll
      for (int i = 0; i < 8; ++i) t[i] = (f16)0.0f;
      if (q == 0) {
        #pragma unroll
        for (int i = 0; i < 6; ++i) t[i] = (f16)(Wih0[R * 6 + i] * sg);
      }
      af[g][2] = t;
      af[g][3] = t;  // unused by team 0
    }
    const float* bi = (team == 1) ? bih1 : bih0;
    const float* bh = (team == 1) ? bhh1 : bhh0;
    const int U = g * 64 + 16 * uw + 4 * q;
    #pragma unroll
    for (int r = 0; r < 4; ++r) bv[g][r] = (bi[U + r] + bh[U + r]) * sg;
  }

  // ---- stage raw x -> LDS f16 (coalesced f32x4) ----
  {
    const float* xblk = x + (size_t)blockIdx.x * (NB * TT * 6);
    #pragma unroll 1
    for (int n = 0; n < NB; ++n) {
      const float* src = xblk + n * (TT * 6);
      f16* dst = xstage + n * XBS;
      for (int idx = tid; idx < TT * 6 / 4; idx += 512) {
        f32x4 v = *(const f32x4*)&src[idx * 4];
        f16x4 h;
        #pragma unroll
        for (int i = 0; i < 4; ++i) h[i] = (f16)v[i];
        *(f16x4*)&dst[idx * 4] = h;
      }
    }
  }
  for (int idx = tid; idx < NB * AUGS; idx += 512) aug0[idx] = (f16)0.0f;
  __syncthreads();

  float cs0 = 0.0f, cs1 = 0.0f;

  const int colb = bcol * AUGS;
  const int xdw = bcol * (XBS / 2);
  const int rowofs = 16 * uw + 4 * q + (lohalf ? 0 : 2);

  auto finish1 = [&](float ai, float afv, float ag, float ao, float& cs) -> f16 {
    float A = 1.0f + fexp2(ai);       // e^{-i}+1  (acc pre-negated)
    float B = 1.0f + fexp2(afv);
    float G = 1.0f + fexp2(ag);       // e^{-2g}+1
    float O = 1.0f + fexp2(ao);
    float d1 = fastrcp(A * B);
    float d2 = fastrcp(G * O);
    float si = d1 * B;
    float sf = d1 * A;
    float tg = __builtin_fmaf(2.0f, d2 * O, -1.0f);
    float so = d2 * G;
    float cn = __builtin_fmaf(sf, cs, si * tg);
    cs = cn;
    float T = 1.0f + fexp2(cn * NC2LE);
    float rT = fastrcp(T);
    return (f16)(__builtin_fmaf(2.0f * so, rT, -so));   // so*tanh(c)
  };

  auto compact_finish = [&](const f32x4* acc) -> f16x2 {
    float u0[4], u1[4];
    #pragma unroll
    for (int g = 0; g < 4; ++g) {
      u0[g] = lohalf ? acc[g][0] : acc[g][2];
      u1[g] = lohalf ? acc[g][1] : acc[g][3];
    }
    f16x2 ho;
    ho[0] = finish1(u0[0], u0[1], u0[2], u0[3], cs0);
    ho[1] = finish1(u1[0], u1[1], u1[2], u1[3], cs1);
    return ho;
  };

  // one pipeline step: team1 L1(t) from cur; team0 L0(t+1) into nxt. Ends with barrier.
  auto STEP = [&](f16* cur, f16* nxt, int t) {
    f16x8 Bh1a = *(const f16x8*)&cur[colb + 64 + 8 * q];
    f16x8 Bh1b = *(const f16x8*)&cur[colb + 96 + 8 * q];
    if (team == 1) {
      f16x8 Bh2a = *(const f16x8*)&cur[colb + 0 + 8 * q];
      f16x8 Bh2b = *(const f16x8*)&cur[colb + 32 + 8 * q];
      f32x4 acc[4];
      #pragma unroll
      for (int g = 0; g < 4; ++g) {
        f32x4 p = __builtin_amdgcn_mfma_f32_16x16x32_f16(af[g][0], Bh2a, bv[g], 0, 0, 0);
        p = __builtin_amdgcn_mfma_f32_16x16x32_f16(af[g][1], Bh2b, p, 0, 0, 0);
        p = __builtin_amdgcn_mfma_f32_16x16x32_f16(af[g][2], Bh1a, p, 0, 0, 0);
        acc[g] = __builtin_amdgcn_mfma_f32_16x16x32_f16(af[g][3], Bh1b, p, 0, 0, 0);
      }
      f16x2 h2o = compact_finish(acc);
      *(f16x2*)&nxt[colb + rowofs] = h2o;                // h2(t)
    } else {
      union { unsigned int un[4]; f16x8 h; } bx;
      const int xo = xdw + 3 * (t + 1);
      bx.un[0] = xw[xo]; bx.un[1] = xw[xo + 1]; bx.un[2] = xw[xo + 2]; bx.un[3] = 0u;
      f32x4 acc[4];
      #pragma unroll
      for (int g = 0; g < 4; ++g) {
        f32x4 p = __builtin_amdgcn_mfma_f32_16x16x32_f16(af[g][0], Bh1a, bv[g], 0, 0, 0);
        p = __builtin_amdgcn_mfma_f32_16x16x32_f16(af[g][1], Bh1b, p, 0, 0, 0);
        acc[g] = __builtin_amdgcn_mfma_f32_16x16x32_f16(af[g][2], bx.h, p, 0, 0, 0);
      }
      f16x2 h1o = compact_finish(acc);
      *(f16x2*)&nxt[colb + 64 + rowofs] = h1o;           // h1(t+1)
    }
    __syncthreads();
  };

  // ---- prologue: team0 computes h1(0) = L0(x(0), 0) ----
  if (team == 0) {
    union { unsigned int un[4]; f16x8 h; } bx;
    bx.un[0] = xw[xdw + 0]; bx.un[1] = xw[xdw + 1]; bx.un[2] = xw[xdw + 2]; bx.un[3] = 0u;
    f32x4 acc[4];
    #pragma unroll
    for (int g = 0; g < 4; ++g)
      acc[g] = __builtin_amdgcn_mfma_f32_16x16x32_f16(af[g][2], bx.h, bv[g], 0, 0, 0);
    f16x2 h1o = compact_finish(acc);
    *(f16x2*)&aug0[colb + 64 + rowofs] = h1o;
  }
  __syncthreads();

  // ---- main loop: 511 steps, manually unrolled x2 with compile-time buffers ----
  #pragma unroll 1
  for (int t = 0; t < TT - 2; t += 2) {
    STEP(aug0, aug1, t);
    STEP(aug1, aug0, t + 1);
  }
  STEP(aug0, aug1, TT - 2);   // t = 510; aug1 now holds {h2(510), h1(511)}

  // ---- epilogue: team1 computes h2(511) from aug1 into aug0 ----
  if (team == 1) {
    f16x8 Bh2a = *(const f16x8*)&aug1[colb + 0 + 8 * q];
    f16x8 Bh2b = *(const f16x8*)&aug1[colb + 32 + 8 * q];
    f16x8 Bh1a = *(const f16x8*)&aug1[colb + 64 + 8 * q];
    f16x8 Bh1b = *(const f16x8*)&aug1[colb + 96 + 8 * q];
    f32x4 acc[4];
    #pragma unroll
    for (int g = 0; g < 4; ++g) {
      f32x4 p = __builtin_amdgcn_mfma_f32_16x16x32_f16(af[g][0], Bh2a, bv[g], 0, 0, 0);
      p = __builtin_amdgcn_mfma_f32_16x16x32_f16(af[g][1], Bh2b, p, 0, 0, 0);
      p = __builtin_amdgcn_mfma_f32_16x16x32_f16(af[g][2], Bh1a, p, 0, 0, 0);
      acc[g] = __builtin_amdgcn_mfma_f32_16x16x32_f16(af[g][3], Bh1b, p, 0, 0, 0);
    }
    f16x2 h2o = compact_finish(acc);
    *(f16x2*)&aug0[colb + rowofs] = h2o;
  }
  __syncthreads();

  // ---- final linear: out[b] = Wlin . h2(511) + blin ----
  if (tid < 48) {
    const int bl = tid / 6, o = tid - bl * 6;
    float s = blin[o];
    const float* wl = &Wlin[o * 64];
    #pragma unroll 8
    for (int u = 0; u < 64; ++u) s += wl[u] * (float)aug0[bl * AUGS + u];
    out[(blockIdx.x * NB + bl) * 6 + o] = s;
  }
}

extern "C" void kernel_launch(void* const* d_in, const int* in_sizes, int n_in,
                              void* d_out, int out_size, void* d_ws, size_t ws_size,
                              hipStream_t stream) {
  const float* xp    = (const float*)d_in[0];
  const float* Wih0  = (const float*)d_in[1];
  const float* Whh0  = (const float*)d_in[2];
  const float* bih0  = (const float*)d_in[3];
  const float* bhh0  = (const float*)d_in[4];
  const float* Wih1  = (const float*)d_in[5];
  const float* Whh1  = (const float*)d_in[6];
  const float* bih1  = (const float*)d_in[7];
  const float* bhh1  = (const float*)d_in[8];
  const float* Wlin  = (const float*)d_in[9];
  const float* blin  = (const float*)d_in[10];
  float* outp = (float*)d_out;

  hipFuncSetAttribute(reinterpret_cast<const void*>(lstm2_kernel),
                      hipFuncAttributeMaxDynamicSharedMemorySize, LDS_BYTES);
  lstm2_kernel<<<256, 512, LDS_BYTES, stream>>>(xp, Wih0, Whh0, bih0, bhh0,
                                                Wih1, Whh1, bih1, bhh1,
                                                Wlin, blin, outp);
}

// Round 21
// 275.403 us; speedup vs baseline: 1.1951x; 1.0072x over previous
//
#include <hip/hip_runtime.h>

typedef _Float16 f16;
typedef _Float16 f16x2 __attribute__((ext_vector_type(2)));
typedef _Float16 f16x4 __attribute__((ext_vector_type(4)));
typedef _Float16 f16x8 __attribute__((ext_vector_type(8)));
typedef float f32x4 __attribute__((ext_vector_type(4)));
typedef unsigned int u32x4 __attribute__((ext_vector_type(4)));

#define NLOG2E -1.4426950408889634f
#define NC2LE  -2.8853900817779268f

__device__ __forceinline__ float fastrcp(float x) { return __builtin_amdgcn_rcpf(x); }
__device__ __forceinline__ float fexp2(float x) { return __builtin_amdgcn_exp2f(x); }

#define TT 512
#define NB 8
/* xstage: f16 [NB][3080] raw x; dw stride 1540 */
#define XBS 3080
#define XS_ELE (NB * XBS)            /* 24640 */
/* aug: [h2(64)|h1(64)|slack] stride 184 f16 = 368B */
#define AUGS 184
#define A0OFF XS_ELE
#define A1OFF (A0OFF + NB * AUGS)
#define LDS_F16 (A1OFF + NB * AUGS)  /* 27584 */
#define LDS_BYTES (LDS_F16 * 2)      /* 55168 B */

__device__ __forceinline__ f16x8 cvt8s(const float* p, float s) {
  f32x4 a = *(const f32x4*)p;
  f32x4 b = *(const f32x4*)(p + 4);
  f16x8 r;
  #pragma unroll
  for (int i = 0; i < 4; ++i) { r[i] = (f16)(a[i] * s); r[4 + i] = (f16)(b[i] * s); }
  return r;
}

__global__ __launch_bounds__(512, 2)
void lstm2_kernel(const float* __restrict__ x,
                  const float* __restrict__ Wih0, const float* __restrict__ Whh0,
                  const float* __restrict__ bih0, const float* __restrict__ bhh0,
                  const float* __restrict__ Wih1, const float* __restrict__ Whh1,
                  const float* __restrict__ bih1, const float* __restrict__ bhh1,
                  const float* __restrict__ Wlin, const float* __restrict__ blin,
                  float* __restrict__ out)
{
  extern __shared__ f16 lds[];
  f16* xstage = lds;
  f16* aug0 = lds + A0OFF;
  f16* aug1 = lds + A1OFF;
  const unsigned int* xw = (const unsigned int*)xstage;

  const int tid = threadIdx.x;
  const int wv = tid >> 6;
  const int team = wv >> 2;        // 0: layer-0 stage, 1: layer-1 stage
  const int uw = wv & 3;           // unit group [16*uw, 16*uw+16)
  const int lane = tid & 63;
  const int m = lane & 15;         // B col; batches = cols 0..7, cols 8..15 mirror
  const int q = lane >> 4;         // k-quarter / C row group
  const bool lohalf = (m < 8);
  const int bcol = m & 7;          // this lane's batch

  // ---- stationary NEGATED-prescaled weights (A fragments) + biases ----
  f16x8 af[4][4];
  f32x4 bv[4];
  #pragma unroll
  for (int g = 0; g < 4; ++g) {
    const float sg = (g == 2) ? NC2LE : NLOG2E;
    const int R = g * 64 + 16 * uw + m;
    if (team == 1) {
      af[g][0] = cvt8s(&Whh1[R * 64 + 8 * q], sg);
      af[g][1] = cvt8s(&Whh1[R * 64 + 32 + 8 * q], sg);
      af[g][2] = cvt8s(&Wih1[R * 64 + 8 * q], sg);
      af[g][3] = cvt8s(&Wih1[R * 64 + 32 + 8 * q], sg);
    } else {
      af[g][0] = cvt8s(&Whh0[R * 64 + 8 * q], sg);
      af[g][1] = cvt8s(&Whh0[R * 64 + 32 + 8 * q], sg);
      f16x8 t;
      #pragma unroll
      for (int i = 0; i < 8; ++i) t[i] = (f16)0.0f;
      if (q == 0) {
        #pragma unroll
        for (int i = 0; i < 6; ++i) t[i] = (f16)(Wih0[R * 6 + i] * sg);
      }
      af[g][2] = t;
    }
    const float* bi = (team == 1) ? bih1 : bih0;
    const float* bh = (team == 1) ? bhh1 : bhh0;
    const int U = g * 64 + 16 * uw + 4 * q;
    #pragma unroll
    for (int r = 0; r < 4; ++r) bv[g][r] = (bi[U + r] + bh[U + r]) * sg;
  }

  // ---- stage raw x -> LDS f16 (coalesced f32x4) ----
  {
    const float* xblk = x + (size_t)blockIdx.x * (NB * TT * 6);
    #pragma unroll 1
    for (int n = 0; n < NB; ++n) {
      const float* src = xblk + n * (TT * 6);
      f16* dst = xstage + n * XBS;
      for (int idx = tid; idx < TT * 6 / 4; idx += 512) {
        f32x4 v = *(const f32x4*)&src[idx * 4];
        f16x4 h;
        #pragma unroll
        for (int i = 0; i < 4; ++i) h[i] = (f16)v[i];
        *(f16x4*)&dst[idx * 4] = h;
      }
    }
  }
  for (int idx = tid; idx < NB * AUGS; idx += 512) aug0[idx] = (f16)0.0f;
  __syncthreads();

  float cs0 = 0.0f, cs1 = 0.0f;

  const int colb = bcol * AUGS;
  const int xdw = bcol * (XBS / 2);
  const int rowofs = 16 * uw + 4 * q + (lohalf ? 0 : 2);

  auto fin_pre = [&](float ai, float afv, float ag, float ao, float& cs,
                     float& so_o, float& cn_o) {
    float A = 1.0f + fexp2(ai);       // e^{-i}+1  (acc pre-negated)
    float B = 1.0f + fexp2(afv);
    float G = 1.0f + fexp2(ag);       // e^{-2g}+1
    float O = 1.0f + fexp2(ao);
    float d1 = fastrcp(A * B);
    float d2 = fastrcp(G * O);
    float si = d1 * B;
    float sf = d1 * A;
    float tg = __builtin_fmaf(2.0f, d2 * O, -1.0f);
    float so = d2 * G;
    float cn = __builtin_fmaf(sf, cs, si * tg);
    cs = cn;
    so_o = so; cn_o = cn;
  };

  auto compact_finish = [&](const f32x4* acc) -> f16x2 {
    float u0[4], u1[4];
    #pragma unroll
    for (int g = 0; g < 4; ++g) {
      u0[g] = lohalf ? acc[g][0] : acc[g][2];
      u1[g] = lohalf ? acc[g][1] : acc[g][3];
    }
    float so0, cn0, so1, cn1;
    fin_pre(u0[0], u0[1], u0[2], u0[3], cs0, so0, cn0);
    fin_pre(u1[0], u1[1], u1[2], u1[3], cs1, so1, cn1);
    float T0 = 1.0f + fexp2(cn0 * NC2LE);
    float T1 = 1.0f + fexp2(cn1 * NC2LE);
    float h0 = __builtin_fmaf(2.0f * so0, fastrcp(T0), -so0);
    float h1 = __builtin_fmaf(2.0f * so1, fastrcp(T1), -so1);
    return __builtin_bit_cast(f16x2, __builtin_amdgcn_cvt_pkrtz(h0, h1));
  };

  // one pipeline step: team1 L1(t) from cur; team0 L0(t+1) into nxt. Ends with barrier.
  auto STEP = [&](f16* cur, f16* nxt, int t) {
    if (team == 1) {
      f16x8 Bh1a = *(const f16x8*)&cur[colb + 64 + 8 * q];
      f16x8 Bh1b = *(const f16x8*)&cur[colb + 96 + 8 * q];
      f16x8 Bh2a = *(const f16x8*)&cur[colb + 0 + 8 * q];
      f16x8 Bh2b = *(const f16x8*)&cur[colb + 32 + 8 * q];
      f32x4 acc[4];
      #pragma unroll
      for (int g = 0; g < 4; ++g) {
        f32x4 p = __builtin_amdgcn_mfma_f32_16x16x32_f16(af[g][0], Bh2a, bv[g], 0, 0, 0);
        p = __builtin_amdgcn_mfma_f32_16x16x32_f16(af[g][1], Bh2b, p, 0, 0, 0);
        p = __builtin_amdgcn_mfma_f32_16x16x32_f16(af[g][2], Bh1a, p, 0, 0, 0);
        acc[g] = __builtin_amdgcn_mfma_f32_16x16x32_f16(af[g][3], Bh1b, p, 0, 0, 0);
      }
      f16x2 h2o = compact_finish(acc);
      *(f16x2*)&nxt[colb + rowofs] = h2o;                // h2(t)
    } else {
      const int xo = xdw + 3 * (t + 1);
      u32x4 uv;
      uv[0] = xw[xo]; uv[1] = xw[xo + 1]; uv[2] = xw[xo + 2]; uv[3] = 0u;
      f16x8 Bh1a = *(const f16x8*)&cur[colb + 64 + 8 * q];
      f16x8 Bh1b = *(const f16x8*)&cur[colb + 96 + 8 * q];
      f16x8 bx = __builtin_bit_cast(f16x8, uv);
      f32x4 acc[4];
      #pragma unroll
      for (int g = 0; g < 4; ++g) {
        f32x4 p = __builtin_amdgcn_mfma_f32_16x16x32_f16(af[g][0], Bh1a, bv[g], 0, 0, 0);
        p = __builtin_amdgcn_mfma_f32_16x16x32_f16(af[g][1], Bh1b, p, 0, 0, 0);
        acc[g] = __builtin_amdgcn_mfma_f32_16x16x32_f16(af[g][2], bx, p, 0, 0, 0);
      }
      f16x2 h1o = compact_finish(acc);
      *(f16x2*)&nxt[colb + 64 + rowofs] = h1o;           // h1(t+1)
    }
    __syncthreads();
  };

  // ---- prologue: team0 computes h1(0) = L0(x(0), 0) ----
  if (team == 0) {
    u32x4 uv;
    uv[0] = xw[xdw + 0]; uv[1] = xw[xdw + 1]; uv[2] = xw[xdw + 2]; uv[3] = 0u;
    f16x8 bx = __builtin_bit_cast(f16x8, uv);
    f32x4 acc[4];
    #pragma unroll
    for (int g = 0; g < 4; ++g)
      acc[g] = __builtin_amdgcn_mfma_f32_16x16x32_f16(af[g][2], bx, bv[g], 0, 0, 0);
    f16x2 h1o = compact_finish(acc);
    *(f16x2*)&aug0[colb + 64 + rowofs] = h1o;
  }
  __syncthreads();

  // ---- main loop: 511 steps, manually unrolled x2 with compile-time buffers ----
  #pragma unroll 1
  for (int t = 0; t < TT - 2; t += 2) {
    STEP(aug0, aug1, t);
    STEP(aug1, aug0, t + 1);
  }
  STEP(aug0, aug1, TT - 2);   // t = 510; aug1 now holds {h2(510), h1(511)}

  // ---- epilogue: team1 computes h2(511) from aug1 into aug0 ----
  if (team == 1) {
    f16x8 Bh2a = *(const f16x8*)&aug1[colb + 0 + 8 * q];
    f16x8 Bh2b = *(const f16x8*)&aug1[colb + 32 + 8 * q];
    f16x8 Bh1a = *(const f16x8*)&aug1[colb + 64 + 8 * q];
    f16x8 Bh1b = *(const f16x8*)&aug1[colb + 96 + 8 * q];
    f32x4 acc[4];
    #pragma unroll
    for (int g = 0; g < 4; ++g) {
      f32x4 p = __builtin_amdgcn_mfma_f32_16x16x32_f16(af[g][0], Bh2a, bv[g], 0, 0, 0);
      p = __builtin_amdgcn_mfma_f32_16x16x32_f16(af[g][1], Bh2b, p, 0, 0, 0);
      p = __builtin_amdgcn_mfma_f32_16x16x32_f16(af[g][2], Bh1a, p, 0, 0, 0);
      acc[g] = __builtin_amdgcn_mfma_f32_16x16x32_f16(af[g][3], Bh1b, p, 0, 0, 0);
    }
    f16x2 h2o = compact_finish(acc);
    *(f16x2*)&aug0[colb + rowofs] = h2o;
  }
  __syncthreads();

  // ---- final linear: out[b] = Wlin . h2(511) + blin ----
  if (tid < 48) {
    const int bl = tid / 6, o = tid - bl * 6;
    float s = blin[o];
    const float* wl = &Wlin[o * 64];
    #pragma unroll 8
    for (int u = 0; u < 64; ++u) s += wl[u] * (float)aug0[bl * AUGS + u];
    out[(blockIdx.x * NB + bl) * 6 + o] = s;
  }
}

extern "C" void kernel_launch(void* const* d_in, const int* in_sizes, int n_in,
                              void* d_out, int out_size, void* d_ws, size_t ws_size,
                              hipStream_t stream) {
  const float* xp    = (const float*)d_in[0];
  const float* Wih0  = (const float*)d_in[1];
  const float* Whh0  = (const float*)d_in[2];
  const float* bih0  = (const float*)d_in[3];
  const float* bhh0  = (const float*)d_in[4];
  const float* Wih1  = (const float*)d_in[5];
  const float* Whh1  = (const float*)d_in[6];
  const float* bih1  = (const float*)d_in[7];
  const float* bhh1  = (const float*)d_in[8];
  const float* Wlin  = (const float*)d_in[9];
  const float* blin  = (const float*)d_in[10];
  float* outp = (float*)d_out;

  hipFuncSetAttribute(reinterpret_cast<const void*>(lstm2_kernel),
                      hipFuncAttributeMaxDynamicSharedMemorySize, LDS_BYTES);
  lstm2_kernel<<<256, 512, LDS_BYTES, stream>>>(xp, Wih0, Whh0, bih0, bhh0,
                                                Wih1, Whh1, bih1, bhh1,
                                                Wlin, blin, outp);
}

// Round 22
// 271.827 us; speedup vs baseline: 1.2108x; 1.0132x over previous
//
#include <hip/hip_runtime.h>

typedef _Float16 f16;
typedef _Float16 f16x2 __attribute__((ext_vector_type(2)));
typedef _Float16 f16x4 __attribute__((ext_vector_type(4)));
typedef _Float16 f16x8 __attribute__((ext_vector_type(8)));
typedef float f32x4 __attribute__((ext_vector_type(4)));
typedef unsigned int u32x4 __attribute__((ext_vector_type(4)));

#define NLOG2E -1.4426950408889634f
#define NC2LE  -2.8853900817779268f

__device__ __forceinline__ float fastrcp(float x) { return __builtin_amdgcn_rcpf(x); }
__device__ __forceinline__ float fexp2(float x) { return __builtin_amdgcn_exp2f(x); }

#define TT 512
#define NB 8
/* xstage: f16 [NB][3080] raw x; dw stride 1540 */
#define XBS 3080
#define XS_ELE (NB * XBS)            /* 24640 */
/* aug: [h2(64)|h1(64)|slack] stride 184 f16 = 368B */
#define AUGS 184
#define A0OFF XS_ELE
#define A1OFF (A0OFF + NB * AUGS)
#define LDS_F16 (A1OFF + NB * AUGS)  /* 27584 */
#define LDS_BYTES (LDS_F16 * 2)      /* 55168 B */

__device__ __forceinline__ f16x8 cvt8s(const float* p, float s) {
  f32x4 a = *(const f32x4*)p;
  f32x4 b = *(const f32x4*)(p + 4);
  f16x8 r;
  #pragma unroll
  for (int i = 0; i < 4; ++i) { r[i] = (f16)(a[i] * s); r[4 + i] = (f16)(b[i] * s); }
  return r;
}

__global__ __launch_bounds__(512, 2)
void lstm2_kernel(const float* __restrict__ x,
                  const float* __restrict__ Wih0, const float* __restrict__ Whh0,
                  const float* __restrict__ bih0, const float* __restrict__ bhh0,
                  const float* __restrict__ Wih1, const float* __restrict__ Whh1,
                  const float* __restrict__ bih1, const float* __restrict__ bhh1,
                  const float* __restrict__ Wlin, const float* __restrict__ blin,
                  float* __restrict__ out)
{
  extern __shared__ f16 lds[];
  f16* xstage = lds;
  f16* aug0 = lds + A0OFF;
  f16* aug1 = lds + A1OFF;
  const unsigned int* xw = (const unsigned int*)xstage;

  const int tid = threadIdx.x;
  const int wv = tid >> 6;
  const int team = wv >> 2;        // 0: layer-0 stage, 1: layer-1 stage
  const int uw = wv & 3;           // unit group [16*uw, 16*uw+16)
  const int lane = tid & 63;
  const int m = lane & 15;         // B col; batches = cols 0..7, cols 8..15 mirror
  const int q = lane >> 4;         // k-quarter / C row group
  const bool lohalf = (m < 8);
  const int bcol = m & 7;          // this lane's batch

  // ---- stationary NEGATED-prescaled weights (A fragments) + biases ----
  f16x8 af[4][4];
  f32x4 bv[4];
  #pragma unroll
  for (int g = 0; g < 4; ++g) {
    const float sg = (g == 2) ? NC2LE : NLOG2E;
    const int R = g * 64 + 16 * uw + m;
    if (team == 1) {
      af[g][0] = cvt8s(&Whh1[R * 64 + 8 * q], sg);
      af[g][1] = cvt8s(&Whh1[R * 64 + 32 + 8 * q], sg);
      af[g][2] = cvt8s(&Wih1[R * 64 + 8 * q], sg);
      af[g][3] = cvt8s(&Wih1[R * 64 + 32 + 8 * q], sg);
    } else {
      af[g][0] = cvt8s(&Whh0[R * 64 + 8 * q], sg);
      af[g][1] = cvt8s(&Whh0[R * 64 + 32 + 8 * q], sg);
      f16x8 t;
      #pragma unroll
      for (int i = 0; i < 8; ++i) t[i] = (f16)0.0f;
      if (q == 0) {
        #pragma unroll
        for (int i = 0; i < 6; ++i) t[i] = (f16)(Wih0[R * 6 + i] * sg);
      }
      af[g][2] = t;
      af[g][3] = t;   // benign init so the register pin below touches defined state
    }
    const float* bi = (team == 1) ? bih1 : bih0;
    const float* bh = (team == 1) ? bhh1 : bhh0;
    const int U = g * 64 + 16 * uw + 4 * q;
    #pragma unroll
    for (int r = 0; r < 4; ++r) bv[g][r] = (bi[U + r] + bh[U + r]) * sg;
  }

  // ---- PIN weights/biases into VGPRs: opaque to the optimizer, so the
  // compiler cannot rematerialize the loads+converts inside the time loop.
  #pragma unroll
  for (int g = 0; g < 4; ++g) {
    #pragma unroll
    for (int k = 0; k < 4; ++k)
      asm volatile("" : "+v"(af[g][k]));
    asm volatile("" : "+v"(bv[g]));
  }

  // ---- stage raw x -> LDS f16 (coalesced f32x4) ----
  {
    const float* xblk = x + (size_t)blockIdx.x * (NB * TT * 6);
    #pragma unroll 1
    for (int n = 0; n < NB; ++n) {
      const float* src = xblk + n * (TT * 6);
      f16* dst = xstage + n * XBS;
      for (int idx = tid; idx < TT * 6 / 4; idx += 512) {
        f32x4 v = *(const f32x4*)&src[idx * 4];
        f16x4 h;
        #pragma unroll
        for (int i = 0; i < 4; ++i) h[i] = (f16)v[i];
        *(f16x4*)&dst[idx * 4] = h;
      }
    }
  }
  for (int idx = tid; idx < NB * AUGS; idx += 512) aug0[idx] = (f16)0.0f;
  __syncthreads();

  float cs0 = 0.0f, cs1 = 0.0f;

  const int colb = bcol * AUGS;
  const int xdw = bcol * (XBS / 2);
  const int rowofs = 16 * uw + 4 * q + (lohalf ? 0 : 2);

  auto fin_pre = [&](float ai, float afv, float ag, float ao, float& cs,
                     float& so_o, float& cn_o) {
    float A = 1.0f + fexp2(ai);       // e^{-i}+1  (acc pre-negated)
    float B = 1.0f + fexp2(afv);
    float G = 1.0f + fexp2(ag);       // e^{-2g}+1
    float O = 1.0f + fexp2(ao);
    float d1 = fastrcp(A * B);
    float d2 = fastrcp(G * O);
    float si = d1 * B;
    float sf = d1 * A;
    float tg = __builtin_fmaf(2.0f, d2 * O, -1.0f);
    float so = d2 * G;
    float cn = __builtin_fmaf(sf, cs, si * tg);
    cs = cn;
    so_o = so; cn_o = cn;
  };

  auto compact_finish = [&](const f32x4* acc) -> f16x2 {
    float u0[4], u1[4];
    #pragma unroll
    for (int g = 0; g < 4; ++g) {
      u0[g] = lohalf ? acc[g][0] : acc[g][2];
      u1[g] = lohalf ? acc[g][1] : acc[g][3];
    }
    float so0, cn0, so1, cn1;
    fin_pre(u0[0], u0[1], u0[2], u0[3], cs0, so0, cn0);
    fin_pre(u1[0], u1[1], u1[2], u1[3], cs1, so1, cn1);
    float T0 = 1.0f + fexp2(cn0 * NC2LE);
    float T1 = 1.0f + fexp2(cn1 * NC2LE);
    float h0 = __builtin_fmaf(2.0f * so0, fastrcp(T0), -so0);
    float h1 = __builtin_fmaf(2.0f * so1, fastrcp(T1), -so1);
    return __builtin_bit_cast(f16x2, __builtin_amdgcn_cvt_pkrtz(h0, h1));
  };

  // one pipeline step: team1 L1(t) from cur; team0 L0(t+1) into nxt. Ends with barrier.
  auto STEP = [&](f16* cur, f16* nxt, int t) {
    if (team == 1) {
      f16x8 Bh1a = *(const f16x8*)&cur[colb + 64 + 8 * q];
      f16x8 Bh1b = *(const f16x8*)&cur[colb + 96 + 8 * q];
      f16x8 Bh2a = *(const f16x8*)&cur[colb + 0 + 8 * q];
      f16x8 Bh2b = *(const f16x8*)&cur[colb + 32 + 8 * q];
      f32x4 acc[4];
      #pragma unroll
      for (int g = 0; g < 4; ++g) {
        f32x4 p = __builtin_amdgcn_mfma_f32_16x16x32_f16(af[g][0], Bh2a, bv[g], 0, 0, 0);
        p = __builtin_amdgcn_mfma_f32_16x16x32_f16(af[g][1], Bh2b, p, 0, 0, 0);
        p = __builtin_amdgcn_mfma_f32_16x16x32_f16(af[g][2], Bh1a, p, 0, 0, 0);
        acc[g] = __builtin_amdgcn_mfma_f32_16x16x32_f16(af[g][3], Bh1b, p, 0, 0, 0);
      }
      f16x2 h2o = compact_finish(acc);
      *(f16x2*)&nxt[colb + rowofs] = h2o;                // h2(t)
    } else {
      const int xo = xdw + 3 * (t + 1);
      u32x4 uv;
      uv[0] = xw[xo]; uv[1] = xw[xo + 1]; uv[2] = xw[xo + 2]; uv[3] = 0u;
      f16x8 Bh1a = *(const f16x8*)&cur[colb + 64 + 8 * q];
      f16x8 Bh1b = *(const f16x8*)&cur[colb + 96 + 8 * q];
      f16x8 bx = __builtin_bit_cast(f16x8, uv);
      f32x4 acc[4];
      #pragma unroll
      for (int g = 0; g < 4; ++g) {
        f32x4 p = __builtin_amdgcn_mfma_f32_16x16x32_f16(af[g][0], Bh1a, bv[g], 0, 0, 0);
        p = __builtin_amdgcn_mfma_f32_16x16x32_f16(af[g][1], Bh1b, p, 0, 0, 0);
        acc[g] = __builtin_amdgcn_mfma_f32_16x16x32_f16(af[g][2], bx, p, 0, 0, 0);
      }
      f16x2 h1o = compact_finish(acc);
      *(f16x2*)&nxt[colb + 64 + rowofs] = h1o;           // h1(t+1)
    }
    __syncthreads();
  };

  // ---- prologue: team0 computes h1(0) = L0(x(0), 0) ----
  if (team == 0) {
    u32x4 uv;
    uv[0] = xw[xdw + 0]; uv[1] = xw[xdw + 1]; uv[2] = xw[xdw + 2]; uv[3] = 0u;
    f16x8 bx = __builtin_bit_cast(f16x8, uv);
    f32x4 acc[4];
    #pragma unroll
    for (int g = 0; g < 4; ++g)
      acc[g] = __builtin_amdgcn_mfma_f32_16x16x32_f16(af[g][2], bx, bv[g], 0, 0, 0);
    f16x2 h1o = compact_finish(acc);
    *(f16x2*)&aug0[colb + 64 + rowofs] = h1o;
  }
  __syncthreads();

  // ---- main loop: 511 steps, manually unrolled x2 with compile-time buffers ----
  #pragma unroll 1
  for (int t = 0; t < TT - 2; t += 2) {
    STEP(aug0, aug1, t);
    STEP(aug1, aug0, t + 1);
  }
  STEP(aug0, aug1, TT - 2);   // t = 510; aug1 now holds {h2(510), h1(511)}

  // ---- epilogue: team1 computes h2(511) from aug1 into aug0 ----
  if (team == 1) {
    f16x8 Bh2a = *(const f16x8*)&aug1[colb + 0 + 8 * q];
    f16x8 Bh2b = *(const f16x8*)&aug1[colb + 32 + 8 * q];
    f16x8 Bh1a = *(const f16x8*)&aug1[colb + 64 + 8 * q];
    f16x8 Bh1b = *(const f16x8*)&aug1[colb + 96 + 8 * q];
    f32x4 acc[4];
    #pragma unroll
    for (int g = 0; g < 4; ++g) {
      f32x4 p = __builtin_amdgcn_mfma_f32_16x16x32_f16(af[g][0], Bh2a, bv[g], 0, 0, 0);
      p = __builtin_amdgcn_mfma_f32_16x16x32_f16(af[g][1], Bh2b, p, 0, 0, 0);
      p = __builtin_amdgcn_mfma_f32_16x16x32_f16(af[g][2], Bh1a, p, 0, 0, 0);
      acc[g] = __builtin_amdgcn_mfma_f32_16x16x32_f16(af[g][3], Bh1b, p, 0, 0, 0);
    }
    f16x2 h2o = compact_finish(acc);
    *(f16x2*)&aug0[colb + rowofs] = h2o;
  }
  __syncthreads();

  // ---- final linear: out[b] = Wlin . h2(511) + blin ----
  if (tid < 48) {
    const int bl = tid / 6, o = tid - bl * 6;
    float s = blin[o];
    const float* wl = &Wlin[o * 64];
    #pragma unroll 8
    for (int u = 0; u < 64; ++u) s += wl[u] * (float)aug0[bl * AUGS + u];
    out[(blockIdx.x * NB + bl) * 6 + o] = s;
  }
}

extern "C" void kernel_launch(void* const* d_in, const int* in_sizes, int n_in,
                              void* d_out, int out_size, void* d_ws, size_t ws_size,
                              hipStream_t stream) {
  const float* xp    = (const float*)d_in[0];
  const float* Wih0  = (const float*)d_in[1];
  const float* Whh0  = (const float*)d_in[2];
  const float* bih0  = (const float*)d_in[3];
  const float* bhh0  = (const float*)d_in[4];
  const float* Wih1  = (const float*)d_in[5];
  const float* Whh1  = (const float*)d_in[6];
  const float* bih1  = (const float*)d_in[7];
  const float* bhh1  = (const float*)d_in[8];
  const float* Wlin  = (const float*)d_in[9];
  const float* blin  = (const float*)d_in[10];
  float* outp = (float*)d_out;

  hipFuncSetAttribute(reinterpret_cast<const void*>(lstm2_kernel),
                      hipFuncAttributeMaxDynamicSharedMemorySize, LDS_BYTES);
  lstm2_kernel<<<256, 512, LDS_BYTES, stream>>>(xp, Wih0, Whh0, bih0, bhh0,
                                                Wih1, Whh1, bih1, bhh1,
                                                Wlin, blin, outp);
}